// Round 12
// baseline (45.800 us; speedup 1.0000x reference)
//
#include <hip/hip_runtime.h>

// Match XLA's elementwise f32 exactly: no FMA contraction on the decision path.
#pragma clang fp contract(off)

#define N_BOX   10647
#define N_CLS   80
#define ROW     85
#define CONF_T  0.8f
#define NMS_T   0.4f
#define NEGV    -1000000000.0f
#define KMAX    256       // max boxes per class (expected ~27, max ~50)
#define OUT_N   3000
#define SURV_N  4096      // survivors cap (expected ~2000)
#define ROWS_PB 56        // rows per block in k_stage; 56*85*4 = 19040 B LDS
#define NBLK_B  ((N_BOX + ROWS_PB - 1) / ROWS_PB)   // 191 blocks
#define CTR_STRIDE 32     // one counter per 128B cacheline
#define CTR_SURV (80 * CTR_STRIDE)
#define CTR_BYTES (82 * 128)

typedef unsigned long long u64;
typedef unsigned int u32;

__device__ __forceinline__ u64 pack_ff(float a, float b) {
    union { float f[2]; u64 u; } x; x.f[0] = a; x.f[1] = b; return x.u;
}
__device__ __forceinline__ u64 pack_fi(float a, int b) {
    union { struct { float f; int i; } s; u64 u; } x; x.s.f = a; x.s.i = b; return x.u;
}
__device__ __forceinline__ float lo_f(u64 v) { union { u64 u; float f[2]; } x; x.u = v; return x.f[0]; }
__device__ __forceinline__ float hi_f(u64 v) { union { u64 u; float f[2]; } x; x.u = v; return x.f[1]; }
__device__ __forceinline__ int   hi_i(u64 v) { union { u64 u; int i[2]; } x; x.u = v; return x.i[1]; }

// ---------- Kernel 1: stage + filter + argmax + bin, and NEG-prefill out ----------
__global__ __launch_bounds__(256) void k_stage(const float* __restrict__ det,
                                               float* __restrict__ out,
                                               int* __restrict__ counters,
                                               u64* __restrict__ pA,
                                               u64* __restrict__ pB,
                                               u64* __restrict__ pS,
                                               u32* __restrict__ pC) {
    __shared__ float lds[ROWS_PB * ROW];   // 19040 B
    const int tid  = threadIdx.x;
    const int bid  = blockIdx.x;
    const int gidx = bid * 256 + tid;

    // NEG-prefill output (covers [0, OUT_N); k_rank later overwrites [0, m))
    if (gidx < OUT_N) out[gidx] = NEGV;

    const int row0 = bid * ROWS_PB;
    int nrows = N_BOX - row0; if (nrows > ROWS_PB) nrows = ROWS_PB;
    if (nrows <= 0) return;

    const int nflt = nrows * ROW;
    const float* src = det + (size_t)row0 * ROW;   // 19040*bid bytes: 16B aligned
    const int n4 = nflt >> 2;
    float4* l4 = (float4*)lds;
    const float4* s4 = (const float4*)src;

    // register-prefetch staging: issue all loads independently, then store.
    {
        const int j0 = tid, j1 = tid + 256, j2 = tid + 512, j3 = tid + 768, j4 = tid + 1024;
        float4 v0, v1, v2, v3, v4;
        if (j0 < n4) v0 = s4[j0];
        if (j1 < n4) v1 = s4[j1];
        if (j2 < n4) v2 = s4[j2];
        if (j3 < n4) v3 = s4[j3];
        if (j4 < n4) v4 = s4[j4];
        if (j0 < n4) l4[j0] = v0;
        if (j1 < n4) l4[j1] = v1;
        if (j2 < n4) l4[j2] = v2;
        if (j3 < n4) l4[j3] = v3;
        if (j4 < n4) l4[j4] = v4;
        for (int j = (n4 << 2) + tid; j < nflt; j += 256) lds[j] = src[j];
    }
    __syncthreads();

    if (tid < nrows) {
        const float* p = lds + tid * ROW;
        float obj = p[4];
        if (obj >= CONF_T) {
            float cx = p[0], cy = p[1], w = p[2], h = p[3];
            float hw = w / 2.0f, hh = h / 2.0f;
            // first-argmax over 80 classes (strict > keeps first = jnp.argmax)
            float best = p[5]; int bcls = 0;
            for (int c = 1; c < N_CLS; ++c) {
                float v = p[5 + c];
                if (v > best) { best = v; bcls = c; }
            }
            int pos = atomicAdd(&counters[bcls * CTR_STRIDE], 1);
            if (pos < KMAX) {
                int o = bcls * KMAX + pos;
                pA[o] = pack_ff(cx - hw, cy - hh);
                pB[o] = pack_ff(cx + hw, cy + hh);
                pS[o] = pack_fi(obj * best, row0 + tid);
                pC[o] = __float_as_uint(best);
            }
        }
    }
}

// ---------- Kernel 2: per-class NMS, ONE WAVE per class ----------
// Single-wave workgroup: barriers compile to waitcnt-only (no cross-wave skew).
__global__ __launch_bounds__(64) void k_nms(const u64* __restrict__ pA,
                                            const u64* __restrict__ pB,
                                            const u64* __restrict__ pS,
                                            const u32* __restrict__ pC,
                                            int* __restrict__ counters,
                                            float* __restrict__ surv) {
    __shared__ float rsc[KMAX]; __shared__ int ridx[KMAX];
    __shared__ float sx1[KMAX], sy1[KMAX], sx2[KMAX], sy2[KMAX], scf[KMAX];
    __shared__ unsigned char alive[KMAX];
    __shared__ float keepc[KMAX];
    __shared__ int nkeep, base;

    const int c = blockIdx.x;
    const int tid = threadIdx.x;
    if (tid == 0) nkeep = 0;

    int k = counters[c * CTR_STRIDE]; if (k > KMAX) k = KMAX;

    for (int i = tid; i < k; i += 64) {
        u64 si = pS[c * KMAX + i];
        rsc[i] = lo_f(si); ridx[i] = hi_i(si);
    }
    __syncthreads();

    // rank = #{j : score[j] > score[i] or (==, idx[j] < idx[i])} -> stable desc
    for (int i = tid; i < k; i += 64) {
        float s = rsc[i]; int id = ridx[i]; int r = 0;
        for (int j = 0; j < k; ++j) {
            float sj = rsc[j];
            r += (sj > s) || (sj == s && ridx[j] < id);
        }
        int o = c * KMAX + i;
        u64 a = pA[o], b = pB[o];
        sx1[r] = lo_f(a); sy1[r] = hi_f(a);
        sx2[r] = lo_f(b); sy2[r] = hi_f(b);
        scf[r] = __uint_as_float(pC[o]);
        alive[r] = 1;
    }
    __syncthreads();

    // greedy NMS with the reference's exact IoU arithmetic (wave-synchronous)
    for (int i = 0; i < k; ++i) {
        bool a = (alive[i] != 0);
        __syncthreads();              // all read alive[i] before lane0 clears it
        if (a) {
            if (tid == 0) { keepc[nkeep++] = scf[i]; alive[i] = 0; }
            float px1 = sx1[i], py1 = sy1[i], px2 = sx2[i], py2 = sy2[i];
            float a1 = ((px2 - px1) + 1.0f) * ((py2 - py1) + 1.0f);
            for (int j = i + 1 + tid; j < k; j += 64) {
                if (!alive[j]) continue;
                float ix1 = fmaxf(px1, sx1[j]);
                float iy1 = fmaxf(py1, sy1[j]);
                float ix2 = fminf(px2, sx2[j]);
                float iy2 = fminf(py2, sy2[j]);
                float iw = fmaxf((ix2 - ix1) + 1.0f, 0.0f);
                float ih = fmaxf((iy2 - iy1) + 1.0f, 0.0f);
                float inter = iw * ih;
                float a2 = ((sx2[j] - sx1[j]) + 1.0f) * ((sy2[j] - sy1[j]) + 1.0f);
                float den = ((a1 + a2) - inter) + 1e-16f;
                if (inter / den > NMS_T) alive[j] = 0;
            }
        }
        __syncthreads();              // suppression visible before next iteration
    }

    if (tid == 0) base = atomicAdd(&counters[CTR_SURV], nkeep);
    __syncthreads();
    int nb = nkeep, b = base;
    for (int i = tid; i < nb; i += 64) {
        int o = b + i;
        if (o < SURV_N) surv[o] = keepc[i];
    }
}

// ---------- Kernel 3: rank-scatter (wave per element, 320 waves) ----------
// Ranks (ties broken by surv index) form a permutation of 0..m-1; out tail
// already NEG from k_stage's prefill.
__global__ __launch_bounds__(256) void k_rank(const float* __restrict__ surv,
                                              const int* __restrict__ counters,
                                              float* __restrict__ out) {
    __shared__ float slds[SURV_N];     // 16 KB
    const int tid = threadIdx.x;
    int m = counters[CTR_SURV]; if (m > SURV_N) m = SURV_N;

    for (int i = tid; i < m; i += 256) slds[i] = surv[i];
    __syncthreads();

    const int lane = tid & 63;
    const int wid  = (blockIdx.x * 256 + tid) >> 6;      // 0..319
    for (int g = wid; g < m; g += N_CLS * 4) {
        const float v = slds[g];
        int cnt = 0;
        for (int j = lane; j < m; j += 64) {
            float sj = slds[j];
            cnt += (sj > v) || (sj == v && j < g);
        }
        #pragma unroll
        for (int off = 32; off > 0; off >>= 1) cnt += __shfl_down(cnt, off, 64);
        if (lane == 0 && cnt < OUT_N) out[cnt] = v;
    }
}

extern "C" void kernel_launch(void* const* d_in, const int* in_sizes, int n_in,
                              void* d_out, int out_size, void* d_ws, size_t ws_size,
                              hipStream_t stream) {
    const float* det = (const float*)d_in[0];
    float* out = (float*)d_out;

    const size_t NB = (size_t)N_CLS * KMAX;     // 20480 entries
    char* p = (char*)d_ws;
    int*   counters = (int*)p;  p += 16384;     // spread counters (128B each)
    u64*   pA   = (u64*)p;      p += NB * 8;    // (x1,y1)
    u64*   pB   = (u64*)p;      p += NB * 8;    // (x2,y2)
    u64*   pS   = (u64*)p;      p += NB * 8;    // (score, idx)
    u32*   pC   = (u32*)p;      p += NB * 4;    // conf
    float* surv = (float*)p;                    // SURV_N floats

    hipMemsetAsync(counters, 0, CTR_BYTES, stream);
    hipLaunchKernelGGL(k_stage, dim3(NBLK_B), dim3(256), 0, stream,
                       det, out, counters, pA, pB, pS, pC);
    hipLaunchKernelGGL(k_nms,   dim3(N_CLS), dim3(64), 0, stream,
                       pA, pB, pS, pC, counters, surv);
    hipLaunchKernelGGL(k_rank,  dim3(N_CLS), dim3(256), 0, stream,
                       surv, counters, out);
}

// Round 13
// 40.652 us; speedup vs baseline: 1.1266x; 1.1266x over previous
//
#include <hip/hip_runtime.h>

// Match XLA's elementwise f32 exactly: no FMA contraction on the decision path.
#pragma clang fp contract(off)

#define N_BOX   10647
#define N_CLS   80
#define ROW     85
#define CONF_T  0.8f
#define NMS_T   0.4f
#define NEGV    -1000000000.0f
#define KMAX    256       // max boxes per class (expected ~27, max ~50)
#define OUT_N   3000
#define SURV_N  4096      // survivors cap (expected ~2000)
#define ROWS_PB 56        // rows per block in k_stage; 56*85*4 = 19040 B LDS
#define NBLK_B  ((N_BOX + ROWS_PB - 1) / ROWS_PB)   // 191 blocks
#define CTR_STRIDE 32     // one counter per 128B cacheline
#define CTR_SURV (80 * CTR_STRIDE)
#define N_CTR_WORDS (82 * CTR_STRIDE)

typedef unsigned long long u64;
typedef unsigned int u32;

__device__ __forceinline__ u64 pack_ff(float a, float b) {
    union { float f[2]; u64 u; } x; x.f[0] = a; x.f[1] = b; return x.u;
}
__device__ __forceinline__ u64 pack_fi(float a, int b) {
    union { struct { float f; int i; } s; u64 u; } x; x.s.f = a; x.s.i = b; return x.u;
}
__device__ __forceinline__ float lo_f(u64 v) { union { u64 u; float f[2]; } x; x.u = v; return x.f[0]; }
__device__ __forceinline__ float hi_f(u64 v) { union { u64 u; float f[2]; } x; x.u = v; return x.f[1]; }
__device__ __forceinline__ int   hi_i(u64 v) { union { u64 u; int i[2]; } x; x.u = v; return x.i[1]; }

// ---------- Kernel 0: zero the (cacheline-spread) counters ----------
__global__ __launch_bounds__(256) void k_init(int* __restrict__ counters) {
    for (int i = threadIdx.x; i < N_CTR_WORDS; i += 256) counters[i] = 0;
}

// ---------- Kernel 1: stage + filter + argmax + bin, and NEG-prefill out ----------
__global__ __launch_bounds__(256) void k_stage(const float* __restrict__ det,
                                               float* __restrict__ out,
                                               int* __restrict__ counters,
                                               u64* __restrict__ pA,
                                               u64* __restrict__ pB,
                                               u64* __restrict__ pS,
                                               u32* __restrict__ pC) {
    __shared__ float lds[ROWS_PB * ROW];   // 19040 B
    const int tid  = threadIdx.x;
    const int bid  = blockIdx.x;
    const int gidx = bid * 256 + tid;

    // NEG-prefill output (covers [0, OUT_N); k_rank later overwrites [0, m))
    if (gidx < OUT_N) out[gidx] = NEGV;

    const int row0 = bid * ROWS_PB;
    int nrows = N_BOX - row0; if (nrows > ROWS_PB) nrows = ROWS_PB;
    if (nrows <= 0) return;

    const int nflt = nrows * ROW;
    const float* src = det + (size_t)row0 * ROW;   // 19040*bid bytes: 16B aligned
    const int n4 = nflt >> 2;
    float4* l4 = (float4*)lds;
    const float4* s4 = (const float4*)src;

    // register-prefetch staging: issue all loads independently, then store.
    {
        const int j0 = tid, j1 = tid + 256, j2 = tid + 512, j3 = tid + 768, j4 = tid + 1024;
        float4 v0, v1, v2, v3, v4;
        if (j0 < n4) v0 = s4[j0];
        if (j1 < n4) v1 = s4[j1];
        if (j2 < n4) v2 = s4[j2];
        if (j3 < n4) v3 = s4[j3];
        if (j4 < n4) v4 = s4[j4];
        if (j0 < n4) l4[j0] = v0;
        if (j1 < n4) l4[j1] = v1;
        if (j2 < n4) l4[j2] = v2;
        if (j3 < n4) l4[j3] = v3;
        if (j4 < n4) l4[j4] = v4;
        for (int j = (n4 << 2) + tid; j < nflt; j += 256) lds[j] = src[j];
    }
    __syncthreads();

    if (tid < nrows) {
        const float* p = lds + tid * ROW;
        float obj = p[4];
        if (obj >= CONF_T) {
            float cx = p[0], cy = p[1], w = p[2], h = p[3];
            float hw = w / 2.0f, hh = h / 2.0f;
            // first-argmax over 80 classes (strict > keeps first = jnp.argmax)
            float best = p[5]; int bcls = 0;
            for (int c = 1; c < N_CLS; ++c) {
                float v = p[5 + c];
                if (v > best) { best = v; bcls = c; }
            }
            int pos = atomicAdd(&counters[bcls * CTR_STRIDE], 1);
            if (pos < KMAX) {
                int o = bcls * KMAX + pos;
                pA[o] = pack_ff(cx - hw, cy - hh);
                pB[o] = pack_ff(cx + hw, cy + hh);
                pS[o] = pack_fi(obj * best, row0 + tid);
                pC[o] = __float_as_uint(best);
            }
        }
    }
}

// ---------- Kernel 2: per-class NMS, ONE WAVE per class ----------
__global__ __launch_bounds__(64) void k_nms(const u64* __restrict__ pA,
                                            const u64* __restrict__ pB,
                                            const u64* __restrict__ pS,
                                            const u32* __restrict__ pC,
                                            int* __restrict__ counters,
                                            float* __restrict__ surv) {
    __shared__ float rsc[KMAX]; __shared__ int ridx[KMAX];
    __shared__ float sx1[KMAX], sy1[KMAX], sx2[KMAX], sy2[KMAX], scf[KMAX];
    __shared__ unsigned char alive[KMAX];
    __shared__ float keepc[KMAX];
    __shared__ int nkeep, base;

    const int c = blockIdx.x;
    const int tid = threadIdx.x;
    if (tid == 0) nkeep = 0;

    int k = counters[c * CTR_STRIDE]; if (k > KMAX) k = KMAX;

    for (int i = tid; i < k; i += 64) {
        u64 si = pS[c * KMAX + i];
        rsc[i] = lo_f(si); ridx[i] = hi_i(si);
    }
    __syncthreads();

    // rank = #{j : score[j] > score[i] or (==, idx[j] < idx[i])} -> stable desc
    for (int i = tid; i < k; i += 64) {
        float s = rsc[i]; int id = ridx[i]; int r = 0;
        for (int j = 0; j < k; ++j) {
            float sj = rsc[j];
            r += (sj > s) || (sj == s && ridx[j] < id);
        }
        int o = c * KMAX + i;
        u64 a = pA[o], b = pB[o];
        sx1[r] = lo_f(a); sy1[r] = hi_f(a);
        sx2[r] = lo_f(b); sy2[r] = hi_f(b);
        scf[r] = __uint_as_float(pC[o]);
        alive[r] = 1;
    }
    __syncthreads();

    // greedy NMS with the reference's exact IoU arithmetic (wave-synchronous)
    for (int i = 0; i < k; ++i) {
        bool a = (alive[i] != 0);
        __syncthreads();              // all read alive[i] before lane0 clears it
        if (a) {
            if (tid == 0) { keepc[nkeep++] = scf[i]; alive[i] = 0; }
            float px1 = sx1[i], py1 = sy1[i], px2 = sx2[i], py2 = sy2[i];
            float a1 = ((px2 - px1) + 1.0f) * ((py2 - py1) + 1.0f);
            for (int j = i + 1 + tid; j < k; j += 64) {
                if (!alive[j]) continue;
                float ix1 = fmaxf(px1, sx1[j]);
                float iy1 = fmaxf(py1, sy1[j]);
                float ix2 = fminf(px2, sx2[j]);
                float iy2 = fminf(py2, sy2[j]);
                float iw = fmaxf((ix2 - ix1) + 1.0f, 0.0f);
                float ih = fmaxf((iy2 - iy1) + 1.0f, 0.0f);
                float inter = iw * ih;
                float a2 = ((sx2[j] - sx1[j]) + 1.0f) * ((sy2[j] - sy1[j]) + 1.0f);
                float den = ((a1 + a2) - inter) + 1e-16f;
                if (inter / den > NMS_T) alive[j] = 0;
            }
        }
        __syncthreads();              // suppression visible before next iteration
    }

    if (tid == 0) base = atomicAdd(&counters[CTR_SURV], nkeep);
    __syncthreads();
    int nb = nkeep, b = base;
    for (int i = tid; i < nb; i += 64) {
        int o = b + i;
        if (o < SURV_N) surv[o] = keepc[i];
    }
}

// ---------- Kernel 3: rank-scatter (wave per element, 1024 waves) ----------
// Ranks (ties broken by surv index) form a permutation of 0..m-1; out tail
// already NEG from k_stage's prefill.
__global__ __launch_bounds__(256) void k_rank(const float* __restrict__ surv,
                                              const int* __restrict__ counters,
                                              float* __restrict__ out) {
    __shared__ float slds[SURV_N];     // 16 KB
    const int tid = threadIdx.x;
    int m = counters[CTR_SURV]; if (m > SURV_N) m = SURV_N;

    for (int i = tid; i < m; i += 256) slds[i] = surv[i];
    __syncthreads();

    const int lane = tid & 63;
    const int wid  = (blockIdx.x * 256 + tid) >> 6;      // 0..1023
    for (int g = wid; g < m; g += 256 * 4) {
        const float v = slds[g];
        int cnt = 0;
        for (int j = lane; j < m; j += 64) {
            float sj = slds[j];
            cnt += (sj > v) || (sj == v && j < g);
        }
        #pragma unroll
        for (int off = 32; off > 0; off >>= 1) cnt += __shfl_down(cnt, off, 64);
        if (lane == 0 && cnt < OUT_N) out[cnt] = v;
    }
}

extern "C" void kernel_launch(void* const* d_in, const int* in_sizes, int n_in,
                              void* d_out, int out_size, void* d_ws, size_t ws_size,
                              hipStream_t stream) {
    const float* det = (const float*)d_in[0];
    float* out = (float*)d_out;

    const size_t NB = (size_t)N_CLS * KMAX;     // 20480 entries
    char* p = (char*)d_ws;
    int*   counters = (int*)p;  p += 16384;     // spread counters (128B each)
    u64*   pA   = (u64*)p;      p += NB * 8;    // (x1,y1)
    u64*   pB   = (u64*)p;      p += NB * 8;    // (x2,y2)
    u64*   pS   = (u64*)p;      p += NB * 8;    // (score, idx)
    u32*   pC   = (u32*)p;      p += NB * 4;    // conf
    float* surv = (float*)p;                    // SURV_N floats

    hipLaunchKernelGGL(k_init,  dim3(1),      dim3(256), 0, stream, counters);
    hipLaunchKernelGGL(k_stage, dim3(NBLK_B), dim3(256), 0, stream,
                       det, out, counters, pA, pB, pS, pC);
    hipLaunchKernelGGL(k_nms,   dim3(N_CLS),  dim3(64),  0, stream,
                       pA, pB, pS, pC, counters, surv);
    hipLaunchKernelGGL(k_rank,  dim3(256),    dim3(256), 0, stream,
                       surv, counters, out);
}